// Round 6
// baseline (1014.513 us; speedup 1.0000x reference)
//
#include <hip/hip_runtime.h>

#define NCH 6
#define NX 32
#define PLANE 1024                  // 32x32 cells per x-plane
#define NCELL (NX * PLANE)
#define CH_STRIDE NCELL
#define STEP_STRIDE (NCH * NCELL)   // floats per history slice
#define NTHREADS PLANE

// ws layout: mbox u64[NX*2*PLANE*NCH] (3.1 MB), then int flags.
// Mailbox record (8B, atomic): (epoch_tag << 32) | f32_bits, epoch_tag = t+1.
// ws poison 0xAAAAAAAA never matches any tag in [1, maxit+1] and is negative
// as int -> all bootstrap checks are poison-safe with zero explicit init.
#define MBOX_WORDS (NX * 2 * PLANE * NCH)
#define F_DONESTEP 0
#define F_CONS 64                   // consumer-epoch slot x at flags[F_CONS + x*16]

typedef unsigned long long u64;

__device__ __forceinline__ u64 ld64(const u64* p) {
    return __hip_atomic_load(p, __ATOMIC_RELAXED, __HIP_MEMORY_SCOPE_SYSTEM);
}
__device__ __forceinline__ void st64(u64* p, u64 v) {
    __hip_atomic_store(p, v, __ATOMIC_RELAXED, __HIP_MEMORY_SCOPE_SYSTEM);
}
__device__ __forceinline__ int ldi(const int* p) {
    return __hip_atomic_load(p, __ATOMIC_RELAXED, __HIP_MEMORY_SCOPE_SYSTEM);
}
__device__ __forceinline__ void sti(int* p, int v) {
    __hip_atomic_store(p, v, __ATOMIC_RELAXED, __HIP_MEMORY_SCOPE_SYSTEM);
}

// Dataflow CA stepper: NO global barrier. Block = x-plane; per-thread x-halo
// exchange via epoch-tagged u64 mailboxes (data-as-flag: tag+payload land in
// one atomic 8B store, so a tag hit means the value is already in hand).
// y/z neighbors via LDS tile. Throttle (2-deep parity mailboxes): producer of
// epoch t+1 requires neighbors consumed epoch t-1. Early-exit is step-stamped:
// target owner publishes done_step=t*; everyone runs through slice t*.
__global__ void __launch_bounds__(NTHREADS, 1)
BEMNA_V7_2_PhaseSpace_44117904064519_kernel(
    const float* __restrict__ D,
    const int* __restrict__ sx_p, const int* __restrict__ sy_p,
    const int* __restrict__ sz_p, const int* __restrict__ ex_p,
    const int* __restrict__ ey_p, const int* __restrict__ ez_p,
    const int* __restrict__ maxit_p,
    float* __restrict__ out,
    u64* __restrict__ mbox,
    int* __restrict__ flags)
{
    __shared__ float tile[2][NCH][PLANE];   // ping-pong own-plane, 49 KB
    __shared__ int lds_ds;                  // block-uniform done_step (-1 unknown)
    volatile int* vds = &lds_ds;

    const int tid = (int)threadIdx.x;       // y*32+z
    const int x   = (int)blockIdx.x;        // plane
    const int y = tid >> 5;
    const int z = tid & 31;
    const int cell = (x << 10) + tid;

    const int sx = *sx_p, sy = *sy_p, sz = *sz_p;
    const int ex = *ex_p, ey = *ey_p, ez = *ez_p;
    const int maxit = *maxit_p;
    const bool is_seed   = (cell == ((sx << 10) | (sy << 5) | sz));
    const bool is_target = (cell == ((ex << 10) | (ey << 5) | ez));

    // o=0 reads (x-1); o=1 (x+1); o=2 (y-1); o=3 (y+1); o=4 (z-1); o=5 (z+1)
    const int  nbg[NCH] = { cell - PLANE, cell + PLANE, cell - 32, cell + 32, cell - 1, cell + 1 };
    const bool ok[NCH]  = { x >= 1, x <= 30, y >= 1, y <= 30, z >= 1, z <= 30 };
    // clamped in-plane indices (value irrelevant when dreg==0)
    const int iym = (tid - 32) & 1023, iyp = (tid + 32) & 1023;
    const int izm = (tid - 1)  & 1023, izp = (tid + 1)  & 1023;

    // D step-invariant: hoist 36 coefficients (zeroed out-of-bounds)
    float dreg[NCH][NCH];
#pragma unroll
    for (int o = 0; o < NCH; ++o)
#pragma unroll
        for (int i = 0; i < NCH; ++i)
            dreg[o][i] = ok[o] ? D[(size_t)(o * NCH + i) * CH_STRIDE + nbg[o]] + 0.95f : 0.0f;

    // ---- init epoch 0: phi_0 regs + tile + mailbox records (tag=1, par=0) ----
    if (tid == 0) lds_ds = -1;
    float myv[NCH];
    const float iv = is_seed ? 1.0f : 0.0f;
    const unsigned ivbits = __float_as_uint(iv);
    u64* mybox0 = &mbox[(((size_t)x * 2 + 0) * PLANE + tid) * NCH];
#pragma unroll
    for (int o = 0; o < NCH; ++o) {
        myv[o] = iv;
        tile[0][o][tid] = iv;
        st64(&mybox0[o], ((u64)1u << 32) | ivbits);
    }
    __syncthreads();

    int tripped = 0;
    int t = 0;
    for (; t < maxit; ++t) {
        // history slice t = phi_t (fire-and-forget)
        float* outp = out + (size_t)t * STEP_STRIDE + cell;
#pragma unroll
        for (int o = 0; o < NCH; ++o) outp[o * CH_STRIDE] = myv[o];

        { const int d = *vds; if (d >= 0 && t >= d) break; }  // slice t* written

        // ---- poll x-halo records for epoch t (tag t+1, parity t&1) ----
        const int par = t & 1;
        const unsigned tagw = (unsigned)(t + 1);
        float phx0[NCH] = {0,0,0,0,0,0}, phx1[NCH] = {0,0,0,0,0,0};
        unsigned pend = (ok[0] ? 0x3fu : 0u) | (ok[1] ? 0xfc0u : 0u);
        const u64* bm = &mbox[(((size_t)(x - 1) * 2 + par) * PLANE + tid) * NCH];
        const u64* bp = &mbox[(((size_t)(x + 1) * 2 + par) * PLANE + tid) * NCH];
        bool thr_ok = (t == 0);    // first overwrite happens at epoch-2 write
        for (;;) {
#pragma unroll
            for (int ch = 0; ch < NCH; ++ch) {
                if (pend & (1u << ch)) {
                    const u64 r = ld64(bm + ch);
                    if ((unsigned)(r >> 32) == tagw) {
                        phx0[ch] = __uint_as_float((unsigned)r);
                        pend &= ~(1u << ch);
                    }
                }
                if (pend & (1u << (ch + 6))) {
                    const u64 r = ld64(bp + ch);
                    if ((unsigned)(r >> 32) == tagw) {
                        phx1[ch] = __uint_as_float((unsigned)r);
                        pend &= ~(1u << (ch + 6));
                    }
                }
            }
            if (tid == 0) {        // master thread: done_step + throttle duty
                const int d = ldi(&flags[F_DONESTEP]);
                if (d >= 0) *vds = d;
                if (!thr_ok) {
                    const int cm = ok[0] ? ldi(&flags[F_CONS + (x - 1) * 16]) : 0x7fffffff;
                    const int cp = ok[1] ? ldi(&flags[F_CONS + (x + 1) * 16]) : 0x7fffffff;
                    thr_ok = (cm >= t - 1) && (cp >= t - 1);
                }
            }
            { const int d = *vds; if (d >= 0 && t >= d) break; }   // abort: data moot
            if (!pend && (tid != 0 || thr_ok)) break;
            __builtin_amdgcn_s_sleep(1);
        }
        __syncthreads();                        // S1: polls done, throttle passed
        { const int d = *vds; if (d >= 0 && t >= d) break; }       // uniform abort

        if (tid == 0) sti(&flags[F_CONS + x * 16], t);  // epoch-t records consumed

        // ---- compute phi_{t+1} ----
        const float (*L)[PLANE] = tile[par];
        float v[NCH];
        {
            float a0 = 0.f, a1 = 0.f, a2 = 0.f, a3 = 0.f, a4 = 0.f, a5 = 0.f;
#pragma unroll
            for (int i = 0; i < NCH; ++i) {
                a0 = fmaf(dreg[0][i], phx0[i], a0);
                a1 = fmaf(dreg[1][i], phx1[i], a1);
                a2 = fmaf(dreg[2][i], L[i][iym], a2);
                a3 = fmaf(dreg[3][i], L[i][iyp], a3);
                a4 = fmaf(dreg[4][i], L[i][izm], a4);
                a5 = fmaf(dreg[5][i], L[i][izp], a5);
            }
            v[0] = fminf(fmaxf(a0, 0.f), 1.f);
            v[1] = fminf(fmaxf(a1, 0.f), 1.f);
            v[2] = fminf(fmaxf(a2, 0.f), 1.f);
            v[3] = fminf(fmaxf(a3, 0.f), 1.f);
            v[4] = fminf(fmaxf(a4, 0.f), 1.f);
            v[5] = fminf(fmaxf(a5, 0.f), 1.f);
        }

        // trip: frozen state is phi_{t+1} -> done_step (first repeated slice) = t+1
        if (is_target && !tripped) {
            if (v[0] + v[1] + v[2] + v[3] + v[4] + v[5] > 0.01f) {
                sti(&flags[F_DONESTEP], t + 1);
                tripped = 1;
            }
        }

        // publish epoch t+1 records (tag t+2, parity (t+1)&1) unless moot
        {
            const int d = *vds;
            if (!(d >= 0 && t + 1 >= d)) {
                u64* mb = &mbox[(((size_t)x * 2 + ((t + 1) & 1)) * PLANE + tid) * NCH];
                const u64 tg = ((u64)(unsigned)(t + 2)) << 32;
#pragma unroll
                for (int o = 0; o < NCH; ++o)
                    st64(&mb[o], tg | __float_as_uint(v[o]));
            }
        }
#pragma unroll
        for (int o = 0; o < NCH; ++o) tile[par ^ 1][o][tid] = v[o];

        __syncthreads();                        // S2: tile[par^1] complete
#pragma unroll
        for (int o = 0; o < NCH; ++o) myv[o] = v[o];
    }
    // nothing to publish: fill derives t* from flags[F_DONESTEP] and reads
    // the frozen state from out[t*] (every block wrote slice t* honestly).
}

// Fill: slices t* + 1 .. maxit-1 := out[t*] (the frozen phi). Pure streaming.
__global__ void fill_kernel(const int* __restrict__ flags,
                            float4* __restrict__ out,
                            int total4)
{
    const int idx4 = blockIdx.x * blockDim.x + threadIdx.x;
    if (idx4 >= total4) return;
    const int s4 = STEP_STRIDE / 4;
    const int maxit = total4 / s4;
    const int ds = flags[F_DONESTEP];
    const int tf = (ds >= 1 && ds <= maxit - 1) ? ds : maxit - 1;
    const int t = idx4 / s4;
    if (t <= tf) return;
    out[idx4] = out[tf * s4 + (idx4 - t * s4)];
}

extern "C" void kernel_launch(void* const* d_in, const int* in_sizes, int n_in,
                              void* d_out, int out_size, void* d_ws, size_t ws_size,
                              hipStream_t stream)
{
    const float* D   = (const float*)d_in[0];
    const int* sx    = (const int*)d_in[1];
    const int* sy    = (const int*)d_in[2];
    const int* sz    = (const int*)d_in[3];
    const int* ex    = (const int*)d_in[4];
    const int* ey    = (const int*)d_in[5];
    const int* ez    = (const int*)d_in[6];
    const int* maxit = (const int*)d_in[7];
    float* out = (float*)d_out;

    u64* mbox  = (u64*)d_ws;                       // 3.1 MB
    int* flags = (int*)(mbox + MBOX_WORDS);

    // 32 blocks x 1024 threads, block = x-plane. No barrier -> plain launch;
    // co-residency by capacity (32 blocks << 256 CUs @ 1 block/CU).
    BEMNA_V7_2_PhaseSpace_44117904064519_kernel<<<dim3(NX), dim3(NTHREADS), 0, stream>>>(
        D, sx, sy, sz, ex, ey, ez, maxit, out, mbox, flags);

    const int total4 = out_size / 4;
    const int fill_blocks = (total4 + 255) / 256;
    fill_kernel<<<dim3(fill_blocks), dim3(256), 0, stream>>>(
        flags, (float4*)out, total4);
}

// Round 7
// 645.588 us; speedup vs baseline: 1.5715x; 1.5715x over previous
//
#include <hip/hip_runtime.h>

#define NCH 6
#define NX 32
#define PLANE 1024                  // 32x32 cells per x-plane
#define NCELL (NX * PLANE)
#define STEP_STRIDE (NCH * NCELL)   // floats per history slice
#define NTHREADS PLANE
#define RB 4                        // ring depth; adjacent-plane skew <=1 -> safe
#define RECW 4                      // u64 words per cell record (6 f32 + pad = 32B)

// flags (ints) after the ring in ws. Poison 0xAAAAAAAA is negative -> all
// >=0 / ==1 checks are bootstrap-safe with zero explicit init.
#define F_DONE 0
#define F_RDY 64                    // ready[x] at flags[F_RDY + x*16], one line each

typedef unsigned long long u64;

__device__ __forceinline__ u64 ld64(const u64* p) {
    return __hip_atomic_load(p, __ATOMIC_RELAXED, __HIP_MEMORY_SCOPE_SYSTEM);
}
__device__ __forceinline__ void st64(u64* p, u64 v) {
    __hip_atomic_store(p, v, __ATOMIC_RELAXED, __HIP_MEMORY_SCOPE_SYSTEM);
}
__device__ __forceinline__ int ldi(const int* p) {
    return __hip_atomic_load(p, __ATOMIC_RELAXED, __HIP_MEMORY_SCOPE_SYSTEM);
}
__device__ __forceinline__ void sti(int* p, int v) {
    __hip_atomic_store(p, v, __ATOMIC_RELAXED, __HIP_MEMORY_SCOPE_SYSTEM);
}
__device__ __forceinline__ u64 pack2(float a, float b) {
    return ((u64)__float_as_uint(b) << 32) | __float_as_uint(a);
}

// Block-flag dataflow stepper: NO global barrier, NO per-thread mailboxes
// (R6 lesson: per-thread sc1 polling amplified traffic 4.5x). Block x
// publishes its plane epoch t+1 into ring slot (t+1)%4 (packed 32B/cell
// records, write-once), drains, sets ready[x]=t+1. Consumer polls ONLY two
// neighbor flags + done (3 sc1 loads/round by tid0), then bulk-loads halos.
// Ring depth 4 needs no consumed-throttle: block x+1 at epoch e implies
// ready[x]>=e-1, so adjacent skew <=1; slot reuse is 4 epochs apart.
__global__ void __launch_bounds__(NTHREADS, 1)
BEMNA_V7_2_PhaseSpace_44117904064519_kernel(
    const float* __restrict__ D,
    const int* __restrict__ sx_p, const int* __restrict__ sy_p,
    const int* __restrict__ sz_p, const int* __restrict__ ex_p,
    const int* __restrict__ ey_p, const int* __restrict__ ez_p,
    const int* __restrict__ maxit_p,
    float* __restrict__ out,
    u64* __restrict__ ring,
    int* __restrict__ flags)
{
    __shared__ float tile[2][NCH][PLANE];   // ping-pong own-plane (y/z neighbors)
    __shared__ int bc;                      // abort broadcast

    const int tid = (int)threadIdx.x;       // y*32+z
    const int x   = (int)blockIdx.x;        // plane
    const int y = tid >> 5;
    const int z = tid & 31;
    const int cell = (x << 10) + tid;

    const int sx = *sx_p, sy = *sy_p, sz = *sz_p;
    const int ex = *ex_p, ey = *ey_p, ez = *ez_p;
    const int maxit = *maxit_p;
    const bool is_seed   = (cell == ((sx << 10) | (sy << 5) | sz));
    const bool is_target = (cell == ((ex << 10) | (ey << 5) | ez));

    // o=0 reads (x-1); o=1 (x+1); o=2 (y-1); o=3 (y+1); o=4 (z-1); o=5 (z+1)
    const int  nbg[NCH] = { cell - PLANE, cell + PLANE, cell - 32, cell + 32, cell - 1, cell + 1 };
    const bool ok[NCH]  = { x >= 1, x <= 30, y >= 1, y <= 30, z >= 1, z <= 30 };
    const int iym = (tid - 32) & 1023, iyp = (tid + 32) & 1023;   // clamped; dreg=0 masks
    const int izm = (tid - 1)  & 1023, izp = (tid + 1)  & 1023;

    // D step-invariant: 36 coefficients in registers (zeroed out-of-bounds)
    float dreg[NCH][NCH];
#pragma unroll
    for (int o = 0; o < NCH; ++o)
#pragma unroll
        for (int i = 0; i < NCH; ++i)
            dreg[o][i] = ok[o] ? D[(size_t)(o * NCH + i) * NCELL + nbg[o]] + 0.95f : 0.0f;

    // ---- init: phi_0, history slice 0, ring slot 0, tile[0] ----
    const float iv = is_seed ? 1.0f : 0.0f;
    {
        u64* rec = ring + ((size_t)0 * NCELL + cell) * RECW;
        const u64 p = pack2(iv, iv);
        st64(rec + 0, p); st64(rec + 1, p); st64(rec + 2, p);
        float* outp = out + cell;
#pragma unroll
        for (int o = 0; o < NCH; ++o) { outp[o * NCELL] = iv; tile[0][o][tid] = iv; }
    }
    __syncthreads();                        // drain (vmcnt) before flag
    if (tid == 0) sti(&flags[F_RDY + x * 16], 0);

    int tripped = 0;
    // iteration t consumes epoch t, produces phi_{t+1} (= history slice t+1)
    for (int t = 0; t <= maxit - 2; ++t) {
        // ---- wait: neighbors ready >= t, or abort if slice t+1 is frozen ----
        if (tid == 0) {
            int ab = 0;
            for (;;) {
                const int dn  = ldi(&flags[F_DONE]);
                const int rdm = (x == 0)      ? 0x7fffffff : ldi(&flags[F_RDY + (x - 1) * 16]);
                const int rdp = (x == NX - 1) ? 0x7fffffff : ldi(&flags[F_RDY + (x + 1) * 16]);
                if (dn >= 0 && t + 1 > dn) { ab = 1; break; }
                if (rdm >= t && rdp >= t) break;
                __builtin_amdgcn_s_sleep(1);
            }
            bc = ab;
        }
        __syncthreads();
        if (bc) break;                      // slices 0..done already written

        // ---- halo loads, epoch t, ring slot t%4 (3 packed u64 per side) ----
        const int slot = t & (RB - 1);
        float phm[NCH], php[NCH];
        if (x >= 1) {
            const u64* rm = ring + ((size_t)slot * NCELL + cell - PLANE) * RECW;
            const u64 a = ld64(rm + 0), b = ld64(rm + 1), c = ld64(rm + 2);
            phm[0] = __uint_as_float((unsigned)a); phm[1] = __uint_as_float((unsigned)(a >> 32));
            phm[2] = __uint_as_float((unsigned)b); phm[3] = __uint_as_float((unsigned)(b >> 32));
            phm[4] = __uint_as_float((unsigned)c); phm[5] = __uint_as_float((unsigned)(c >> 32));
        } else {
#pragma unroll
            for (int i = 0; i < NCH; ++i) phm[i] = 0.0f;
        }
        if (x <= NX - 2) {
            const u64* rp = ring + ((size_t)slot * NCELL + cell + PLANE) * RECW;
            const u64 a = ld64(rp + 0), b = ld64(rp + 1), c = ld64(rp + 2);
            php[0] = __uint_as_float((unsigned)a); php[1] = __uint_as_float((unsigned)(a >> 32));
            php[2] = __uint_as_float((unsigned)b); php[3] = __uint_as_float((unsigned)(b >> 32));
            php[4] = __uint_as_float((unsigned)c); php[5] = __uint_as_float((unsigned)(c >> 32));
        } else {
#pragma unroll
            for (int i = 0; i < NCH; ++i) php[i] = 0.0f;
        }

        // ---- compute phi_{t+1} ----
        const float (*L)[PLANE] = tile[t & 1];
        float v[NCH];
        {
            float a0 = 0.f, a1 = 0.f, a2 = 0.f, a3 = 0.f, a4 = 0.f, a5 = 0.f;
#pragma unroll
            for (int i = 0; i < NCH; ++i) {
                a0 = fmaf(dreg[0][i], phm[i], a0);
                a1 = fmaf(dreg[1][i], php[i], a1);
                a2 = fmaf(dreg[2][i], L[i][iym], a2);
                a3 = fmaf(dreg[3][i], L[i][iyp], a3);
                a4 = fmaf(dreg[4][i], L[i][izm], a4);
                a5 = fmaf(dreg[5][i], L[i][izp], a5);
            }
            v[0] = fminf(fmaxf(a0, 0.f), 1.f);
            v[1] = fminf(fmaxf(a1, 0.f), 1.f);
            v[2] = fminf(fmaxf(a2, 0.f), 1.f);
            v[3] = fminf(fmaxf(a3, 0.f), 1.f);
            v[4] = fminf(fmaxf(a4, 0.f), 1.f);
            v[5] = fminf(fmaxf(a5, 0.f), 1.f);
        }

        // trip: phi_{t+1} is the frozen state -> done_step = t+1
        if (is_target && !tripped) {
            if (v[0] + v[1] + v[2] + v[3] + v[4] + v[5] > 0.01f) {
                sti(&flags[F_DONE], t + 1);
                tripped = 1;
            }
        }

        // ---- publish epoch t+1: ring (sc1) + history slice t+1 (plain) + tile
        {
            u64* rec = ring + ((size_t)((t + 1) & (RB - 1)) * NCELL + cell) * RECW;
            st64(rec + 0, pack2(v[0], v[1]));
            st64(rec + 1, pack2(v[2], v[3]));
            st64(rec + 2, pack2(v[4], v[5]));
            float* outp = out + (size_t)(t + 1) * STEP_STRIDE + cell;
#pragma unroll
            for (int o = 0; o < NCH; ++o) {
                outp[o * NCELL] = v[o];
                tile[(t + 1) & 1][o][tid] = v[o];
            }
        }
        __syncthreads();                    // drain ring+history stores, tile done
        if (tid == 0) sti(&flags[F_RDY + x * 16], t + 1);
    }
}

// 2D fill: grid (48 chunks, maxit slices), 256 threads, 4 float4/thread.
// Slices <= t* exit as whole blocks. Source = out[t*] (cross-kernel visible).
__global__ void fill_kernel(const int* __restrict__ flags,
                            float4* __restrict__ out)
{
    const int s4 = STEP_STRIDE / 4;         // 49152 float4 per slice
    const int t = (int)blockIdx.y;
    const int maxit = (int)gridDim.y;
    const int ds = flags[F_DONE];
    const int tf = (ds >= 1 && ds <= maxit - 1) ? ds : maxit - 1;
    if (t <= tf) return;
    const int base = (int)blockIdx.x * 1024 + (int)threadIdx.x;
#pragma unroll
    for (int k = 0; k < 4; ++k) {
        const int off = base + k * 256;
        out[(size_t)t * s4 + off] = out[(size_t)tf * s4 + off];
    }
}

extern "C" void kernel_launch(void* const* d_in, const int* in_sizes, int n_in,
                              void* d_out, int out_size, void* d_ws, size_t ws_size,
                              hipStream_t stream)
{
    const float* D   = (const float*)d_in[0];
    const int* sx    = (const int*)d_in[1];
    const int* sy    = (const int*)d_in[2];
    const int* sz    = (const int*)d_in[3];
    const int* ex    = (const int*)d_in[4];
    const int* ey    = (const int*)d_in[5];
    const int* ez    = (const int*)d_in[6];
    const int* maxit = (const int*)d_in[7];
    float* out = (float*)d_out;

    u64* ring  = (u64*)d_ws;                           // 4 slots x 1 MB = 4.2 MB
    int* flags = (int*)(ring + (size_t)RB * NCELL * RECW);

    // 32 blocks x 1024 threads, block = x-plane; plain launch (no barrier).
    BEMNA_V7_2_PhaseSpace_44117904064519_kernel<<<dim3(NX), dim3(NTHREADS), 0, stream>>>(
        D, sx, sy, sz, ex, ey, ez, maxit, out, ring, flags);

    // maxit == out_size / STEP_STRIDE (host-known); 48 chunks x 1024 float4.
    const int slices = out_size / STEP_STRIDE;
    fill_kernel<<<dim3(48, slices), dim3(256), 0, stream>>>(flags, (float4*)out);
}

// Round 8
// 438.373 us; speedup vs baseline: 2.3143x; 1.4727x over previous
//
#include <hip/hip_runtime.h>

#define NCH 6
#define NX 32
#define PLANE 1024                  // 32x32 cells per x-plane
#define NCELL (NX * PLANE)
#define STEP_STRIDE (NCH * NCELL)   // floats per history slice
#define NTHREADS 256                // one y-stripe (8 rows x 32 z) of a plane
#define NBLOCKS 128                 // 32 planes x 4 y-stripes
#define RB 4                        // ring depth; adjacent skew <=1 -> safe

// ws: u64 ring[RB][3][NCELL] (SoA streams -> full-line coalescing; R7's 8B
// stride-32 stores caused ~4x fabric write amplification), then int flags.
// Poison 0xAAAAAAAA is negative -> all >=0 checks bootstrap-safe, no init.
#define RING_WORDS ((size_t)RB * 3 * NCELL)
#define F_DONE 0
#define F_RDY 64                    // ready[b] at flags[F_RDY + b*16]

typedef unsigned long long u64;

__device__ __forceinline__ u64 ld64(const u64* p) {
    return __hip_atomic_load(p, __ATOMIC_RELAXED, __HIP_MEMORY_SCOPE_SYSTEM);
}
__device__ __forceinline__ void st64(u64* p, u64 v) {
    __hip_atomic_store(p, v, __ATOMIC_RELAXED, __HIP_MEMORY_SCOPE_SYSTEM);
}
__device__ __forceinline__ int ldi(const int* p) {
    return __hip_atomic_load(p, __ATOMIC_RELAXED, __HIP_MEMORY_SCOPE_SYSTEM);
}
__device__ __forceinline__ void sti(int* p, int v) {
    __hip_atomic_store(p, v, __ATOMIC_RELAXED, __HIP_MEMORY_SCOPE_SYSTEM);
}
__device__ __forceinline__ u64 pack2(float a, float b) {
    return ((u64)__float_as_uint(b) << 32) | __float_as_uint(a);
}

// Dataflow stepper, block = (x-plane, y-stripe). Per epoch a block publishes
// its 256-cell stripe into ring slot (t+1)%4 as 3 coalesced u64 streams,
// drains (syncthreads -> vmcnt0 all waves), sets ready[b]=t+1, THEN issues
// history stores (their HBM acks overlap the next poll). Consumer tid0 polls
// 4 neighbor flags + done; x+-1 halos and y-stripe boundary rows come from
// the ring; in-stripe y/z from an LDS tile. Early exit is step-stamped.
__global__ void __launch_bounds__(NTHREADS)
BEMNA_V7_2_PhaseSpace_44117904064519_kernel(
    const float* __restrict__ D,
    const int* __restrict__ sx_p, const int* __restrict__ sy_p,
    const int* __restrict__ sz_p, const int* __restrict__ ex_p,
    const int* __restrict__ ey_p, const int* __restrict__ ez_p,
    const int* __restrict__ maxit_p,
    float* __restrict__ out,
    u64* __restrict__ ring,
    int* __restrict__ flags)
{
    __shared__ float tile[2][NCH][NTHREADS];   // ping-pong own stripe, 12 KB
    __shared__ int bc;

    const int tid = (int)threadIdx.x;          // yl*32+z
    const int bx  = (int)blockIdx.x;
    const int x   = bx >> 2;                   // plane
    const int s   = bx & 3;                    // y-stripe
    const int yl  = tid >> 5;                  // 0..7
    const int z   = tid & 31;
    const int y   = (s << 3) + yl;
    const int cell = (x << 10) + (y << 5) + z; // == x*1024 + s*256 + tid

    const int sx = *sx_p, sy = *sy_p, sz = *sz_p;
    const int ex = *ex_p, ey = *ey_p, ez = *ez_p;
    const int maxit = *maxit_p;
    const bool is_seed   = (cell == ((sx << 10) | (sy << 5) | sz));
    const bool is_target = (cell == ((ex << 10) | (ey << 5) | ez));

    // o=0 reads (x-1); o=1 (x+1); o=2 (y-1); o=3 (y+1); o=4 (z-1); o=5 (z+1)
    const int  nbg[NCH] = { cell - PLANE, cell + PLANE, cell - 32, cell + 32, cell - 1, cell + 1 };
    const bool ok[NCH]  = { x >= 1, x <= 30, y >= 1, y <= 30, z >= 1, z <= 30 };
    const int izm = (tid - 1) & (NTHREADS - 1), izp = (tid + 1) & (NTHREADS - 1); // dreg masks bounds

    // D step-invariant: 36 coefficients in registers (zeroed out-of-bounds)
    float dreg[NCH][NCH];
#pragma unroll
    for (int o = 0; o < NCH; ++o)
#pragma unroll
        for (int i = 0; i < NCH; ++i)
            dreg[o][i] = ok[o] ? D[(size_t)(o * NCH + i) * NCELL + nbg[o]] + 0.95f : 0.0f;

    // ---- init: epoch 0 -> ring slot 0, history slice 0, tile[0] ----
    const float iv = is_seed ? 1.0f : 0.0f;
    {
        const u64 p = pack2(iv, iv);
        st64(&ring[(0 * 3 + 0) * NCELL + cell], p);
        st64(&ring[(0 * 3 + 1) * NCELL + cell], p);
        st64(&ring[(0 * 3 + 2) * NCELL + cell], p);
        float* outp = out + cell;
#pragma unroll
        for (int o = 0; o < NCH; ++o) { outp[o * NCELL] = iv; tile[0][o][tid] = iv; }
    }
    __syncthreads();                           // drain before flag
    if (tid == 0) sti(&flags[F_RDY + bx * 16], 0);

    int tripped = 0;
    // iteration t consumes epoch t, produces phi_{t+1} (= history slice t+1)
    for (int t = 0; t <= maxit - 2; ++t) {
        // ---- wait for 4 neighbors ready >= t, or abort if slice t+1 frozen ----
        if (tid == 0) {
            int ab = 0;
            for (;;) {
                const int dn = ldi(&flags[F_DONE]);
                int r = 0x7fffffff;
                if (x >= 1)  r = min(r, ldi(&flags[F_RDY + (bx - 4) * 16]));
                if (x <= 30) r = min(r, ldi(&flags[F_RDY + (bx + 4) * 16]));
                if (s >= 1)  r = min(r, ldi(&flags[F_RDY + (bx - 1) * 16]));
                if (s <= 2)  r = min(r, ldi(&flags[F_RDY + (bx + 1) * 16]));
                if (dn >= 0 && t + 1 > dn) { ab = 1; break; }
                if (r >= t) break;
                __builtin_amdgcn_s_sleep(1);
            }
            bc = ab;
        }
        __syncthreads();                       // also drains prior history stores
        if (bc) break;                         // slices 0..done already written

        // ---- halo loads from ring slot t%4 (coalesced SoA streams) ----
        const u64* rs = ring + (size_t)(t & (RB - 1)) * 3 * NCELL;
        float phm[NCH], php[NCH], pym[NCH], pyp[NCH];
        if (x >= 1) {
            const u64 a = ld64(rs + 0 * NCELL + cell - PLANE);
            const u64 b = ld64(rs + 1 * NCELL + cell - PLANE);
            const u64 c = ld64(rs + 2 * NCELL + cell - PLANE);
            phm[0] = __uint_as_float((unsigned)a); phm[1] = __uint_as_float((unsigned)(a >> 32));
            phm[2] = __uint_as_float((unsigned)b); phm[3] = __uint_as_float((unsigned)(b >> 32));
            phm[4] = __uint_as_float((unsigned)c); phm[5] = __uint_as_float((unsigned)(c >> 32));
        } else {
#pragma unroll
            for (int i = 0; i < NCH; ++i) phm[i] = 0.0f;
        }
        if (x <= 30) {
            const u64 a = ld64(rs + 0 * NCELL + cell + PLANE);
            const u64 b = ld64(rs + 1 * NCELL + cell + PLANE);
            const u64 c = ld64(rs + 2 * NCELL + cell + PLANE);
            php[0] = __uint_as_float((unsigned)a); php[1] = __uint_as_float((unsigned)(a >> 32));
            php[2] = __uint_as_float((unsigned)b); php[3] = __uint_as_float((unsigned)(b >> 32));
            php[4] = __uint_as_float((unsigned)c); php[5] = __uint_as_float((unsigned)(c >> 32));
        } else {
#pragma unroll
            for (int i = 0; i < NCH; ++i) php[i] = 0.0f;
        }
        const bool ym_ring = (yl == 0) && (y >= 1);   // stripe-boundary rows
        const bool yp_ring = (yl == 7) && (y <= 30);
        if (ym_ring) {
            const u64 a = ld64(rs + 0 * NCELL + cell - 32);
            const u64 b = ld64(rs + 1 * NCELL + cell - 32);
            const u64 c = ld64(rs + 2 * NCELL + cell - 32);
            pym[0] = __uint_as_float((unsigned)a); pym[1] = __uint_as_float((unsigned)(a >> 32));
            pym[2] = __uint_as_float((unsigned)b); pym[3] = __uint_as_float((unsigned)(b >> 32));
            pym[4] = __uint_as_float((unsigned)c); pym[5] = __uint_as_float((unsigned)(c >> 32));
        }
        if (yp_ring) {
            const u64 a = ld64(rs + 0 * NCELL + cell + 32);
            const u64 b = ld64(rs + 1 * NCELL + cell + 32);
            const u64 c = ld64(rs + 2 * NCELL + cell + 32);
            pyp[0] = __uint_as_float((unsigned)a); pyp[1] = __uint_as_float((unsigned)(a >> 32));
            pyp[2] = __uint_as_float((unsigned)b); pyp[3] = __uint_as_float((unsigned)(b >> 32));
            pyp[4] = __uint_as_float((unsigned)c); pyp[5] = __uint_as_float((unsigned)(c >> 32));
        }

        // ---- compute phi_{t+1} ----
        const float (*L)[NTHREADS] = tile[t & 1];
        if (!ym_ring) {
            const int n = (tid - 32) & (NTHREADS - 1);
#pragma unroll
            for (int i = 0; i < NCH; ++i) pym[i] = L[i][n];   // dreg[2]=0 if y==0
        }
        if (!yp_ring) {
            const int n = (tid + 32) & (NTHREADS - 1);
#pragma unroll
            for (int i = 0; i < NCH; ++i) pyp[i] = L[i][n];   // dreg[3]=0 if y==31
        }
        float v[NCH];
        {
            float a0 = 0.f, a1 = 0.f, a2 = 0.f, a3 = 0.f, a4 = 0.f, a5 = 0.f;
#pragma unroll
            for (int i = 0; i < NCH; ++i) {
                a0 = fmaf(dreg[0][i], phm[i], a0);
                a1 = fmaf(dreg[1][i], php[i], a1);
                a2 = fmaf(dreg[2][i], pym[i], a2);
                a3 = fmaf(dreg[3][i], pyp[i], a3);
                a4 = fmaf(dreg[4][i], L[i][izm], a4);
                a5 = fmaf(dreg[5][i], L[i][izp], a5);
            }
            v[0] = fminf(fmaxf(a0, 0.f), 1.f);
            v[1] = fminf(fmaxf(a1, 0.f), 1.f);
            v[2] = fminf(fmaxf(a2, 0.f), 1.f);
            v[3] = fminf(fmaxf(a3, 0.f), 1.f);
            v[4] = fminf(fmaxf(a4, 0.f), 1.f);
            v[5] = fminf(fmaxf(a5, 0.f), 1.f);
        }

        // trip: phi_{t+1} is the frozen state -> done_step = t+1
        if (is_target && !tripped) {
            if (v[0] + v[1] + v[2] + v[3] + v[4] + v[5] > 0.01f) {
                sti(&flags[F_DONE], t + 1);
                tripped = 1;
            }
        }

        // ---- publish epoch t+1: ring slot (t+1)%4 (SoA) + tile; drain; flag
        {
            u64* ws_ = ring + (size_t)((t + 1) & (RB - 1)) * 3 * NCELL;
            st64(ws_ + 0 * NCELL + cell, pack2(v[0], v[1]));
            st64(ws_ + 1 * NCELL + cell, pack2(v[2], v[3]));
            st64(ws_ + 2 * NCELL + cell, pack2(v[4], v[5]));
#pragma unroll
            for (int o = 0; o < NCH; ++o) tile[(t + 1) & 1][o][tid] = v[o];
        }
        __syncthreads();                       // vmcnt0 all waves -> ring visible
        if (tid == 0) sti(&flags[F_RDY + bx * 16], t + 1);

        // history slice t+1 AFTER the flag: HBM acks overlap the next poll
        {
            float* outp = out + (size_t)(t + 1) * STEP_STRIDE + cell;
#pragma unroll
            for (int o = 0; o < NCH; ++o) outp[o * NCELL] = v[o];
        }
    }
}

// 2D fill: slices t*+1 .. maxit-1 := out[t*]. Whole blocks exit for t <= t*.
__global__ void fill_kernel(const int* __restrict__ flags,
                            float4* __restrict__ out)
{
    const int s4 = STEP_STRIDE / 4;
    const int t = (int)blockIdx.y;
    const int maxit = (int)gridDim.y;
    const int ds = flags[F_DONE];
    const int tf = (ds >= 1 && ds <= maxit - 1) ? ds : maxit - 1;
    if (t <= tf) return;
    const int base = (int)blockIdx.x * 1024 + (int)threadIdx.x;
#pragma unroll
    for (int k = 0; k < 4; ++k) {
        const int off = base + k * 256;
        out[(size_t)t * s4 + off] = out[(size_t)tf * s4 + off];
    }
}

extern "C" void kernel_launch(void* const* d_in, const int* in_sizes, int n_in,
                              void* d_out, int out_size, void* d_ws, size_t ws_size,
                              hipStream_t stream)
{
    const float* D   = (const float*)d_in[0];
    const int* sx    = (const int*)d_in[1];
    const int* sy    = (const int*)d_in[2];
    const int* sz    = (const int*)d_in[3];
    const int* ex    = (const int*)d_in[4];
    const int* ey    = (const int*)d_in[5];
    const int* ez    = (const int*)d_in[6];
    const int* maxit = (const int*)d_in[7];
    float* out = (float*)d_out;

    u64* ring  = (u64*)d_ws;                   // 4 x 3 x 32768 x 8B = 3.1 MB
    int* flags = (int*)(ring + RING_WORDS);

    // 128 blocks x 256 threads (x-plane x y-stripe); plain launch, dataflow
    // sync. Co-residency by capacity (128 blocks << 256 CUs @ 1 block/CU).
    BEMNA_V7_2_PhaseSpace_44117904064519_kernel<<<dim3(NBLOCKS), dim3(NTHREADS), 0, stream>>>(
        D, sx, sy, sz, ex, ey, ez, maxit, out, ring, flags);

    const int slices = out_size / STEP_STRIDE;
    fill_kernel<<<dim3(48, slices), dim3(256), 0, stream>>>(flags, (float4*)out);
}